// Round 1
// baseline (828.334 us; speedup 1.0000x reference)
//
#include <hip/hip_runtime.h>

#define NPTS   1000000
#define NFEAT  64
#define GRIDN  100
#define NBINS  1000000   // GRIDN^3

#define SCAN_B    256    // threads per scan block
#define SCAN_I    4      // items per thread
#define SCAN_TILE 1024   // SCAN_B * SCAN_I (must stay 1024: k_scan3 uses >>10)
#define NBLK      977    // ceil(NBINS / SCAN_TILE)

// --- 1. histogram: key per point, count per bin ---
__global__ void k_count(const int* __restrict__ coors, int* __restrict__ keys,
                        int* __restrict__ count, int n) {
    int p = blockIdx.x * blockDim.x + threadIdx.x;
    if (p >= n) return;
    int c0 = coors[p * 3 + 0];
    int c1 = coors[p * 3 + 1];
    int c2 = coors[p * 3 + 2];
    int key = (c0 * GRIDN + c1) * GRIDN + c2;
    keys[p] = key;
    atomicAdd(&count[key], 1);
}

// --- 2a. per-block dual exclusive scan (occupancy, count) + block totals ---
__global__ void k_scan1(const int* __restrict__ count, int* __restrict__ rank,
                        int* __restrict__ pstart, int* __restrict__ blkOcc,
                        int* __restrict__ blkCnt) {
    __shared__ int sOcc[SCAN_B], sCnt[SCAN_B];
    int tid  = threadIdx.x;
    int base = blockIdx.x * SCAN_TILE + tid * SCAN_I;
    int locO[SCAN_I], locC[SCAN_I];
    int tOcc = 0, tCnt = 0;
    #pragma unroll
    for (int i = 0; i < SCAN_I; ++i) {
        int idx = base + i;
        int v = (idx < NBINS) ? count[idx] : 0;
        locO[i] = tOcc; locC[i] = tCnt;          // thread-local exclusive
        tOcc += (v > 0) ? 1 : 0;
        tCnt += v;
    }
    sOcc[tid] = tOcc; sCnt[tid] = tCnt;
    __syncthreads();
    // Hillis-Steele inclusive scan over 256 thread totals
    for (int ofs = 1; ofs < SCAN_B; ofs <<= 1) {
        int vo = 0, vc = 0;
        if (tid >= ofs) { vo = sOcc[tid - ofs]; vc = sCnt[tid - ofs]; }
        __syncthreads();
        sOcc[tid] += vo; sCnt[tid] += vc;
        __syncthreads();
    }
    int exO = sOcc[tid] - tOcc;                  // thread exclusive offset
    int exC = sCnt[tid] - tCnt;
    #pragma unroll
    for (int i = 0; i < SCAN_I; ++i) {
        int idx = base + i;
        if (idx < NBINS) {
            rank[idx]   = exO + locO[i];
            pstart[idx] = exC + locC[i];
        }
    }
    if (tid == SCAN_B - 1) {
        blkOcc[blockIdx.x] = sOcc[tid];          // block totals (inclusive of last)
        blkCnt[blockIdx.x] = sCnt[tid];
    }
}

// --- 2b. single-block scan of block totals -> exclusive offsets; M total ---
__global__ void k_scan2(int* __restrict__ blkOcc, int* __restrict__ blkCnt,
                        int* __restrict__ m_dev) {
    __shared__ int sO[1024], sC[1024];
    int tid = threadIdx.x;
    int vO = (tid < NBLK) ? blkOcc[tid] : 0;
    int vC = (tid < NBLK) ? blkCnt[tid] : 0;
    sO[tid] = vO; sC[tid] = vC;
    __syncthreads();
    for (int ofs = 1; ofs < 1024; ofs <<= 1) {
        int a = 0, b = 0;
        if (tid >= ofs) { a = sO[tid - ofs]; b = sC[tid - ofs]; }
        __syncthreads();
        sO[tid] += a; sC[tid] += b;
        __syncthreads();
    }
    if (tid < NBLK) {
        blkOcc[tid] = sO[tid] - vO;              // exclusive
        blkCnt[tid] = sC[tid] - vC;
    }
    if (tid == 1023) *m_dev = sO[1023];          // total occupied voxels M
}

// --- 2c. add block offsets ---
__global__ void k_scan3(int* __restrict__ rank, int* __restrict__ pstart,
                        const int* __restrict__ blkOcc, const int* __restrict__ blkCnt) {
    int i = blockIdx.x * blockDim.x + threadIdx.x;
    if (i >= NBINS) return;
    int b = i >> 10;                             // / SCAN_TILE
    rank[i]   += blkOcc[b];
    pstart[i] += blkCnt[b];
}

// --- 3. counting-sort fill: perm holds point indices grouped by bin ---
__global__ void k_fill(const int* __restrict__ keys, int* __restrict__ pstart,
                       int* __restrict__ perm, int n) {
    int p = blockIdx.x * blockDim.x + threadIdx.x;
    if (p >= n) return;
    int pos = atomicAdd(&pstart[keys[p]], 1);    // pstart[bin] ends at range end
    perm[pos] = p;
}

// --- 4. one wave per bin: mean-reduce + coors decode + padding rows ---
__global__ void k_mean(const float* __restrict__ feats, const int* __restrict__ count,
                       const int* __restrict__ pstart, const int* __restrict__ rank,
                       const int* __restrict__ perm, const int* __restrict__ m_dev,
                       float* __restrict__ out) {
    int gid  = blockIdx.x * blockDim.x + threadIdx.x;
    int bin  = gid >> 6;                         // wave id
    int lane = gid & 63;                         // feature channel
    if (bin >= NBINS) return;
    float* out_coors = out + (size_t)NBINS * NFEAT;  // 64,000,000 floats in
    int cnt = count[bin];
    if (cnt > 0) {
        int end   = pstart[bin];                 // after k_fill: start + cnt
        int start = end - cnt;
        int r     = rank[bin];
        float s = 0.f;
        for (int j = start; j < end; ++j) {
            int p = perm[j];
            s += feats[p * NFEAT + lane];        // 256 B contiguous row, coalesced
        }
        out[r * NFEAT + lane] = s / (float)cnt;
        if (lane < 3) {
            int v = (lane == 0) ? bin / (GRIDN * GRIDN)
                  : (lane == 1) ? (bin / GRIDN) % GRIDN
                  :               bin % GRIDN;
            out_coors[r * 3 + lane] = (float)v;
        }
    }
    int M = *m_dev;
    if (bin >= M) {                              // padding row (row index == bin)
        out[bin * NFEAT + lane] = 0.f;
        if (lane < 3) out_coors[bin * 3 + lane] = -1.f;
    }
}

extern "C" void kernel_launch(void* const* d_in, const int* in_sizes, int n_in,
                              void* d_out, int out_size, void* d_ws, size_t ws_size,
                              hipStream_t stream) {
    const float* feats = (const float*)d_in[0];
    const int*   coors = (const int*)d_in[1];
    float*       out   = (float*)d_out;
    int n = in_sizes[1] / 3;                     // 1,000,000 points

    // workspace carve (ints): keys | count | rank | pstart | perm | blkOcc | blkCnt | m
    int* keys   = (int*)d_ws;
    int* count  = keys   + NPTS;
    int* rank   = count  + NBINS;
    int* pstart = rank   + NBINS;
    int* perm   = pstart + NBINS;
    int* blkOcc = perm   + NPTS;
    int* blkCnt = blkOcc + NBLK;
    int* m_dev  = blkCnt + NBLK;

    hipMemsetAsync(count, 0, NBINS * sizeof(int), stream);

    int b = 256;
    k_count<<<(n + b - 1) / b, b, 0, stream>>>(coors, keys, count, n);
    k_scan1<<<NBLK, SCAN_B, 0, stream>>>(count, rank, pstart, blkOcc, blkCnt);
    k_scan2<<<1, 1024, 0, stream>>>(blkOcc, blkCnt, m_dev);
    k_scan3<<<(NBINS + b - 1) / b, b, 0, stream>>>(rank, pstart, blkOcc, blkCnt);
    k_fill<<<(n + b - 1) / b, b, 0, stream>>>(keys, pstart, perm, n);
    // one 64-lane wave per bin: NBINS*64 threads
    k_mean<<<(NBINS * 64) / b, b, 0, stream>>>(feats, count, pstart, rank, perm,
                                               m_dev, out);
}

// Round 2
// 593.097 us; speedup vs baseline: 1.3966x; 1.3966x over previous
//
#include <hip/hip_runtime.h>

#define NPTS   1000000
#define NFEAT  64
#define GRIDN  100
#define NBINS  1000000   // GRIDN^3

#define SCAN_B    256    // threads per scan block
#define SCAN_I    4      // items per thread
#define SCAN_TILE 1024   // SCAN_B * SCAN_I (must stay 1024: k_scan3 uses >>10)
#define NBLK      977    // ceil(NBINS / SCAN_TILE)

// --- 1. histogram: key per point, count per bin ---
__global__ void k_count(const int* __restrict__ coors, int* __restrict__ keys,
                        int* __restrict__ count, int n) {
    int p = blockIdx.x * blockDim.x + threadIdx.x;
    if (p >= n) return;
    int c0 = coors[p * 3 + 0];
    int c1 = coors[p * 3 + 1];
    int c2 = coors[p * 3 + 2];
    int key = (c0 * GRIDN + c1) * GRIDN + c2;
    keys[p] = key;
    atomicAdd(&count[key], 1);
}

// --- 2a. per-block dual exclusive scan (occupancy, count) + block totals ---
__global__ void k_scan1(const int* __restrict__ count, int* __restrict__ rank,
                        int* __restrict__ pstart, int* __restrict__ blkOcc,
                        int* __restrict__ blkCnt) {
    __shared__ int sOcc[SCAN_B], sCnt[SCAN_B];
    int tid  = threadIdx.x;
    int base = blockIdx.x * SCAN_TILE + tid * SCAN_I;
    int locO[SCAN_I], locC[SCAN_I];
    int tOcc = 0, tCnt = 0;
    #pragma unroll
    for (int i = 0; i < SCAN_I; ++i) {
        int idx = base + i;
        int v = (idx < NBINS) ? count[idx] : 0;
        locO[i] = tOcc; locC[i] = tCnt;          // thread-local exclusive
        tOcc += (v > 0) ? 1 : 0;
        tCnt += v;
    }
    sOcc[tid] = tOcc; sCnt[tid] = tCnt;
    __syncthreads();
    // Hillis-Steele inclusive scan over 256 thread totals
    for (int ofs = 1; ofs < SCAN_B; ofs <<= 1) {
        int vo = 0, vc = 0;
        if (tid >= ofs) { vo = sOcc[tid - ofs]; vc = sCnt[tid - ofs]; }
        __syncthreads();
        sOcc[tid] += vo; sCnt[tid] += vc;
        __syncthreads();
    }
    int exO = sOcc[tid] - tOcc;                  // thread exclusive offset
    int exC = sCnt[tid] - tCnt;
    #pragma unroll
    for (int i = 0; i < SCAN_I; ++i) {
        int idx = base + i;
        if (idx < NBINS) {
            rank[idx]   = exO + locO[i];
            pstart[idx] = exC + locC[i];
        }
    }
    if (tid == SCAN_B - 1) {
        blkOcc[blockIdx.x] = sOcc[tid];          // block totals (inclusive of last)
        blkCnt[blockIdx.x] = sCnt[tid];
    }
}

// --- 2b. single-block scan of block totals -> exclusive offsets; M total ---
__global__ void k_scan2(int* __restrict__ blkOcc, int* __restrict__ blkCnt,
                        int* __restrict__ m_dev) {
    __shared__ int sO[1024], sC[1024];
    int tid = threadIdx.x;
    int vO = (tid < NBLK) ? blkOcc[tid] : 0;
    int vC = (tid < NBLK) ? blkCnt[tid] : 0;
    sO[tid] = vO; sC[tid] = vC;
    __syncthreads();
    for (int ofs = 1; ofs < 1024; ofs <<= 1) {
        int a = 0, b = 0;
        if (tid >= ofs) { a = sO[tid - ofs]; b = sC[tid - ofs]; }
        __syncthreads();
        sO[tid] += a; sC[tid] += b;
        __syncthreads();
    }
    if (tid < NBLK) {
        blkOcc[tid] = sO[tid] - vO;              // exclusive
        blkCnt[tid] = sC[tid] - vC;
    }
    if (tid == 1023) *m_dev = sO[1023];          // total occupied voxels M
}

// --- 2c. add block offsets; emit packed per-output-row records ---
// rowinfo[r] = { start, bin | (cnt<<20) }   (bin < 2^20, cnt < 2^12 safe)
__global__ void k_scan3(const int* __restrict__ rank, int* __restrict__ pstart,
                        const int* __restrict__ blkOcc, const int* __restrict__ blkCnt,
                        const int* __restrict__ count, int2* __restrict__ rowinfo) {
    int i = blockIdx.x * blockDim.x + threadIdx.x;
    if (i >= NBINS) return;
    int b  = i >> 10;                            // / SCAN_TILE
    int ps = pstart[i] + blkCnt[b];
    pstart[i] = ps;                              // final start, consumed by k_fill
    int c = count[i];
    if (c > 0) {
        int r = rank[i] + blkOcc[b];
        rowinfo[r] = make_int2(ps, i | (c << 20));
    }
}

// --- 3. counting-sort fill: perm holds point indices grouped by bin ---
__global__ void k_fill(const int* __restrict__ keys, int* __restrict__ pstart,
                       int* __restrict__ perm, int n) {
    int p = blockIdx.x * blockDim.x + threadIdx.x;
    if (p >= n) return;
    int pos = atomicAdd(&pstart[keys[p]], 1);
    perm[pos] = p;
}

// --- 4. row-centric mean: 16 lanes (float4 each) per output row, 4 rows/wave ---
__global__ void k_mean(const float4* __restrict__ feats4,
                       const int2* __restrict__ rowinfo,
                       const int* __restrict__ perm,
                       const int* __restrict__ m_dev,
                       float4* __restrict__ out4) {
    int gid = blockIdx.x * blockDim.x + threadIdx.x;
    int row = gid >> 4;                          // output row
    int sub = gid & 15;                          // covers channels sub*4 .. sub*4+3
    if (row >= NBINS) return;
    float* out_coors = (float*)(out4 + (size_t)NBINS * 16);  // after 64M floats
    int M = *m_dev;
    if (row < M) {
        int2 info = rowinfo[row];
        int start = info.x;
        int bin   = info.y & 0xFFFFF;
        int cnt   = info.y >> 20;
        int gbase = (threadIdx.x & 63) & ~15;    // wave-lane base of this 16-group
        float4 s = make_float4(0.f, 0.f, 0.f, 0.f);
        for (int b0 = 0; b0 < cnt; b0 += 16) {
            int rem = cnt - b0;
            int lim = rem < 16 ? rem : 16;
            int pv  = (sub < lim) ? perm[start + b0 + sub] : 0;
            for (int j = 0; j < lim; ++j) {
                int pj = __shfl(pv, gbase + j);  // broadcast point idx in group
                float4 f = feats4[pj * 16 + sub];  // 256 B coalesced per group
                s.x += f.x; s.y += f.y; s.z += f.z; s.w += f.w;
            }
        }
        float inv = 1.0f / (float)cnt;
        s.x *= inv; s.y *= inv; s.z *= inv; s.w *= inv;
        out4[(size_t)row * 16 + sub] = s;
        if (sub < 3) {
            int v = (sub == 0) ? bin / (GRIDN * GRIDN)
                  : (sub == 1) ? (bin / GRIDN) % GRIDN
                  :               bin % GRIDN;
            out_coors[row * 3 + sub] = (float)v;
        }
    } else {                                     // padding row
        out4[(size_t)row * 16 + sub] = make_float4(0.f, 0.f, 0.f, 0.f);
        if (sub < 3) out_coors[row * 3 + sub] = -1.f;
    }
}

extern "C" void kernel_launch(void* const* d_in, const int* in_sizes, int n_in,
                              void* d_out, int out_size, void* d_ws, size_t ws_size,
                              hipStream_t stream) {
    const float* feats = (const float*)d_in[0];
    const int*   coors = (const int*)d_in[1];
    float*       out   = (float*)d_out;
    int n = in_sizes[1] / 3;                     // 1,000,000 points

    // workspace carve (ints): keys | count | rank | pstart | perm | rowinfo(2N) | blkOcc | blkCnt | m
    int*  keys    = (int*)d_ws;
    int*  count   = keys   + NPTS;
    int*  rank    = count  + NBINS;
    int*  pstart  = rank   + NBINS;
    int*  perm    = pstart + NBINS;
    int2* rowinfo = (int2*)(perm + NPTS);        // 5M ints in -> 8B aligned
    int*  blkOcc  = (int*)(rowinfo + NBINS);
    int*  blkCnt  = blkOcc + NBLK;
    int*  m_dev   = blkCnt + NBLK;

    hipMemsetAsync(count, 0, NBINS * sizeof(int), stream);

    int b = 256;
    k_count<<<(n + b - 1) / b, b, 0, stream>>>(coors, keys, count, n);
    k_scan1<<<NBLK, SCAN_B, 0, stream>>>(count, rank, pstart, blkOcc, blkCnt);
    k_scan2<<<1, 1024, 0, stream>>>(blkOcc, blkCnt, m_dev);
    k_scan3<<<(NBINS + b - 1) / b, b, 0, stream>>>(rank, pstart, blkOcc, blkCnt,
                                                   count, rowinfo);
    k_fill<<<(n + b - 1) / b, b, 0, stream>>>(keys, pstart, perm, n);
    // 16 lanes per row, NBINS rows -> 16M threads
    k_mean<<<(NBINS * 16) / b, b, 0, stream>>>((const float4*)feats, rowinfo, perm,
                                               m_dev, (float4*)out);
}

// Round 3
// 558.412 us; speedup vs baseline: 1.4834x; 1.0621x over previous
//
#include <hip/hip_runtime.h>

#define NPTS   1000000
#define NFEAT  64
#define GRIDN  100
#define NBINS  1000000   // GRIDN^3

#define SCAN_B    256    // threads per scan block
#define SCAN_I    4      // items per thread
#define SCAN_TILE 1024   // SCAN_B * SCAN_I
#define NBLK      977    // ceil(NBINS / SCAN_TILE)

// --- 1. histogram: key per point, count per bin ---
__global__ void k_count(const int* __restrict__ coors, int* __restrict__ keys,
                        int* __restrict__ count, int n) {
    int p = blockIdx.x * blockDim.x + threadIdx.x;
    if (p >= n) return;
    int c0 = coors[p * 3 + 0];
    int c1 = coors[p * 3 + 1];
    int c2 = coors[p * 3 + 2];
    int key = (c0 * GRIDN + c1) * GRIDN + c2;
    keys[p] = key;
    atomicAdd(&count[key], 1);
}

// --- 2a. block totals only (occupancy, count) ---
__global__ void k_scan1(const int4* __restrict__ count4, int* __restrict__ blkOcc,
                        int* __restrict__ blkCnt) {
    __shared__ int sO[SCAN_B], sC[SCAN_B];
    int tid  = threadIdx.x;
    int base = blockIdx.x * SCAN_TILE + tid * SCAN_I;
    int tO = 0, tC = 0;
    if (base < NBINS) {                          // NBINS % 4 == 0 -> whole int4 valid
        int4 v = count4[base >> 2];
        tO = (v.x > 0) + (v.y > 0) + (v.z > 0) + (v.w > 0);
        tC = v.x + v.y + v.z + v.w;
    }
    sO[tid] = tO; sC[tid] = tC;
    __syncthreads();
    for (int ofs = SCAN_B / 2; ofs > 0; ofs >>= 1) {
        if (tid < ofs) { sO[tid] += sO[tid + ofs]; sC[tid] += sC[tid + ofs]; }
        __syncthreads();
    }
    if (tid == 0) { blkOcc[blockIdx.x] = sO[0]; blkCnt[blockIdx.x] = sC[0]; }
}

// --- 2b. single-block scan of block totals -> exclusive offsets; M total ---
__global__ void k_scan2(int* __restrict__ blkOcc, int* __restrict__ blkCnt,
                        int* __restrict__ m_dev) {
    __shared__ int sO[1024], sC[1024];
    int tid = threadIdx.x;
    int vO = (tid < NBLK) ? blkOcc[tid] : 0;
    int vC = (tid < NBLK) ? blkCnt[tid] : 0;
    sO[tid] = vO; sC[tid] = vC;
    __syncthreads();
    for (int ofs = 1; ofs < 1024; ofs <<= 1) {
        int a = 0, b = 0;
        if (tid >= ofs) { a = sO[tid - ofs]; b = sC[tid - ofs]; }
        __syncthreads();
        sO[tid] += a; sC[tid] += b;
        __syncthreads();
    }
    if (tid < NBLK) {
        blkOcc[tid] = sO[tid] - vO;              // exclusive
        blkCnt[tid] = sC[tid] - vC;
    }
    if (tid == 1023) *m_dev = sO[1023];          // total occupied voxels M
}

// --- 2c. local dual scan + global offsets; emit pstart, rankstart, rowinfo.xy ---
// rankstart[bin] = (rank << 32) | start   (both < 2^20)
// rowinfo[r]     = { start, bin | cnt<<20, p0 (by k_fill), p1 (by k_fill) }
__global__ void k_scan3(const int4* __restrict__ count4, int4* __restrict__ pstart4,
                        const int* __restrict__ blkOcc, const int* __restrict__ blkCnt,
                        long long* __restrict__ rankstart, int4* __restrict__ rowinfo) {
    __shared__ int sO[SCAN_B], sC[SCAN_B];
    int tid  = threadIdx.x;
    int base = blockIdx.x * SCAN_TILE + tid * SCAN_I;
    int4 v = make_int4(0, 0, 0, 0);
    if (base < NBINS) v = count4[base >> 2];
    int c[SCAN_I] = {v.x, v.y, v.z, v.w};
    int locO[SCAN_I], locC[SCAN_I];
    int tO = 0, tC = 0;
    #pragma unroll
    for (int i = 0; i < SCAN_I; ++i) {
        locO[i] = tO; locC[i] = tC;
        tO += (c[i] > 0) ? 1 : 0;
        tC += c[i];
    }
    sO[tid] = tO; sC[tid] = tC;
    __syncthreads();
    for (int ofs = 1; ofs < SCAN_B; ofs <<= 1) {   // Hillis-Steele inclusive
        int a = 0, b = 0;
        if (tid >= ofs) { a = sO[tid - ofs]; b = sC[tid - ofs]; }
        __syncthreads();
        sO[tid] += a; sC[tid] += b;
        __syncthreads();
    }
    if (base >= NBINS) return;
    int exO = sO[tid] - tO + blkOcc[blockIdx.x];
    int exC = sC[tid] - tC + blkCnt[blockIdx.x];
    int4 ps;
    ps.x = exC + locC[0]; ps.y = exC + locC[1];
    ps.z = exC + locC[2]; ps.w = exC + locC[3];
    pstart4[base >> 2] = ps;
    int psa[SCAN_I] = {ps.x, ps.y, ps.z, ps.w};
    #pragma unroll
    for (int i = 0; i < SCAN_I; ++i) {
        if (c[i] > 0) {
            int bin = base + i;
            int r   = exO + locO[i];
            rankstart[bin] = ((long long)r << 32) | (long long)psa[i];
            *(int2*)(&rowinfo[r]) = make_int2(psa[i], bin | (c[i] << 20));
        }
    }
}

// --- 3. fill: first two points of each row inline into rowinfo, rest to perm ---
__global__ void k_fill(const int* __restrict__ keys, int* __restrict__ pstart,
                       const long long* __restrict__ rankstart,
                       int* __restrict__ perm, int4* __restrict__ rowinfo, int n) {
    int p = blockIdx.x * blockDim.x + threadIdx.x;
    if (p >= n) return;
    int k = keys[p];
    int pos = atomicAdd(&pstart[k], 1);          // independent of rankstart load
    long long rs = rankstart[k];
    int start = (int)(rs & 0xFFFFFFFFLL);
    int r     = (int)(rs >> 32);
    int j = pos - start;
    if (j < 2) ((int*)rowinfo)[r * 4 + 2 + j] = p;   // p0 / p1 slots
    else       perm[pos] = p;
}

// --- 4. row-centric mean: 16 lanes (float4 each) per output row ---
__global__ void k_mean(const float4* __restrict__ feats4,
                       const int4* __restrict__ rowinfo,
                       const int* __restrict__ perm,
                       const int* __restrict__ m_dev,
                       float4* __restrict__ out4) {
    int gid = blockIdx.x * blockDim.x + threadIdx.x;
    int row = gid >> 4;                          // output row
    int sub = gid & 15;                          // channels sub*4 .. sub*4+3
    if (row >= NBINS) return;
    float* out_coors = (float*)(out4 + (size_t)NBINS * 16);  // after 64M floats
    int M = *m_dev;
    if (row < M) {
        int4 info = rowinfo[row];
        int start = info.x;
        int bin   = info.y & 0xFFFFF;
        int cnt   = info.y >> 20;
        float4 s = feats4[(size_t)info.z * 16 + sub];        // p0: always valid
        if (cnt > 1) {
            float4 f = feats4[(size_t)info.w * 16 + sub];    // p1
            s.x += f.x; s.y += f.y; s.z += f.z; s.w += f.w;
        }
        if (cnt > 2) {                           // 13% of rows: tail via perm
            int gbase = (threadIdx.x & 63) & ~15;
            for (int b0 = 2; b0 < cnt; b0 += 16) {
                int rem = cnt - b0;
                int lim = rem < 16 ? rem : 16;
                int pv  = (sub < lim) ? perm[start + b0 + sub] : 0;
                for (int j = 0; j < lim; ++j) {
                    int pj = __shfl(pv, gbase + j);
                    float4 f = feats4[(size_t)pj * 16 + sub];
                    s.x += f.x; s.y += f.y; s.z += f.z; s.w += f.w;
                }
            }
        }
        float inv = 1.0f / (float)cnt;
        s.x *= inv; s.y *= inv; s.z *= inv; s.w *= inv;
        out4[(size_t)row * 16 + sub] = s;
        if (sub < 3) {
            int v = (sub == 0) ? bin / (GRIDN * GRIDN)
                  : (sub == 1) ? (bin / GRIDN) % GRIDN
                  :               bin % GRIDN;
            out_coors[row * 3 + sub] = (float)v;
        }
    } else {                                     // padding row
        out4[(size_t)row * 16 + sub] = make_float4(0.f, 0.f, 0.f, 0.f);
        if (sub < 3) out_coors[row * 3 + sub] = -1.f;
    }
}

extern "C" void kernel_launch(void* const* d_in, const int* in_sizes, int n_in,
                              void* d_out, int out_size, void* d_ws, size_t ws_size,
                              hipStream_t stream) {
    const float* feats = (const float*)d_in[0];
    const int*   coors = (const int*)d_in[1];
    float*       out   = (float*)d_out;
    int n = in_sizes[1] / 3;                     // 1,000,000 points

    // ws carve: keys | count | pstart | perm | rowinfo(int4) | rankstart(ll) | blk | m
    int*       keys      = (int*)d_ws;
    int*       count     = keys   + NPTS;
    int*       pstart    = count  + NBINS;
    int*       perm      = pstart + NBINS;
    int4*      rowinfo   = (int4*)(perm + NPTS);            // 16 MB, 16B-aligned
    long long* rankstart = (long long*)(rowinfo + NBINS);   // 8 MB
    int*       blkOcc    = (int*)(rankstart + NBINS);
    int*       blkCnt    = blkOcc + NBLK;
    int*       m_dev     = blkCnt + NBLK;

    hipMemsetAsync(count, 0, NBINS * sizeof(int), stream);

    int b = 256;
    k_count<<<(n + b - 1) / b, b, 0, stream>>>(coors, keys, count, n);
    k_scan1<<<NBLK, SCAN_B, 0, stream>>>((const int4*)count, blkOcc, blkCnt);
    k_scan2<<<1, 1024, 0, stream>>>(blkOcc, blkCnt, m_dev);
    k_scan3<<<NBLK, SCAN_B, 0, stream>>>((const int4*)count, (int4*)pstart,
                                         blkOcc, blkCnt, rankstart, rowinfo);
    k_fill<<<(n + b - 1) / b, b, 0, stream>>>(keys, pstart, rankstart, perm,
                                              rowinfo, n);
    k_mean<<<(NBINS * 16) / b, b, 0, stream>>>((const float4*)feats, rowinfo, perm,
                                               m_dev, (float4*)out);
}